// Round 18
// baseline (79.278 us; speedup 1.0000x reference)
//
#include <hip/hip_runtime.h>
#include <hip/hip_fp16.h>

// KGCN forward, MI355X. R18 = R17 with s_h deleted (aliased onto s_pre).
// Safety: Af fragment ds_reads are issued (values bound, in-order DS) before
// the h-writes; iter-1 reads h rows before overwriting row 0 in program
// order; rows are per-wave-disjoint. LDS 40,448 -> 30,656 B: static cap
// 3 -> 5 blocks/CU. Single-variable test of whether block residency was
// LDS-capped (occupancy counter is fallback-formula on gfx950, so the
// measured "11 waves/CU" may under-report the cap's effect). If dur is
// unchanged, the latency-chain floor is confirmed.

namespace {

constexpr int kDim      = 64;
constexpr int kNN       = 8;
constexpr int kNumEnt   = 100000;
constexpr int kItemInKG = 20000;
constexpr int kElems    = 8;     // batch elements (waves) per block
constexpr int kRelChunks = 976;  // 61 rel rows * 16 float4 chunks
constexpr int kP        = 68;    // fp16 row stride (136B)
constexpr size_t kEntHalfBytes = (size_t)(kNumEnt + 1) * kDim * sizeof(__half);

typedef _Float16 f16x4 __attribute__((ext_vector_type(4)));
typedef _Float16 f16x8 __attribute__((ext_vector_type(8)));
typedef float    f32x4 __attribute__((ext_vector_type(4)));

__device__ __forceinline__ float fast_sigmoid(float x) {
  return 1.0f / (1.0f + __expf(-x));
}
__device__ __forceinline__ float fast_tanh(float x) {
  return 2.0f / (1.0f + __expf(-2.0f * x)) - 1.0f;
}
__device__ __forceinline__ float readlane_f(float v, int lane) {
  return __int_as_float(__builtin_amdgcn_readlane(__float_as_int(v), lane));
}
__device__ __forceinline__ f16x8 join8(f16x4 lo, f16x4 hi) {
  return __builtin_shufflevector(lo, hi, 0, 1, 2, 3, 4, 5, 6, 7);
}
__device__ __forceinline__ f16x4 cvt4(float4 f) {
  f16x4 h;
  h[0] = (_Float16)f.x; h[1] = (_Float16)f.y;
  h[2] = (_Float16)f.z; h[3] = (_Float16)f.w;
  return h;
}

// ---- pre-pass: ent_emb fp32 -> fp16 into workspace ----
__global__ void __launch_bounds__(256)
conv_kernel(const float* __restrict__ src, __half2* __restrict__ dst, int n4) {
  const int i = blockIdx.x * 256 + threadIdx.x;
  if (i < n4) {
    const float4 f = reinterpret_cast<const float4*>(src)[i];
    dst[2 * i + 0] = __floats2half2_rn(f.x, f.y);
    dst[2 * i + 1] = __floats2half2_rn(f.z, f.w);
  }
}

template <bool HALF>
__global__ void __launch_bounds__(kElems * 64)
__attribute__((amdgpu_waves_per_eu(4)))
kgcn_kernel(const int* __restrict__ u, const int* __restrict__ v,
            const float* __restrict__ usr_emb, const float* __restrict__ item_emb,
            const float* __restrict__ ent_emb, const __half* __restrict__ ent_h,
            const float* __restrict__ rel_emb,
            const float* __restrict__ W, const float* __restrict__ bias,
            const int* __restrict__ adj_ent, const int* __restrict__ adj_rel,
            float* __restrict__ out)
{
  const int tid = threadIdx.x;
  const int wv  = tid >> 6;
  const int ln  = tid & 63;
  const int lq  = ln & 15;    // MFMA m/n index
  const int lg  = ln >> 4;    // MFMA k-slot group
  const int b   = blockIdx.x * kElems + wv;

  __shared__ __align__(16) _Float16 s_wh[kDim * kP];      // 8,704 B
  __shared__ __align__(16) _Float16 s_relh[kDim * kP];    // 8,704 B
  __shared__ __align__(16) _Float16 s_ueh[kElems * kDim]; // 1,024 B
  __shared__ __align__(16) _Float16 s_pre[72 * kP];       // 9,792 B (pre AND h)
  __shared__ float s_w2[kElems][kDim];                    // 2,048 B
  // total 30,272 B + pad -> ~30.7KB: 5 blocks/CU static (was 3)

  // ---- staging loads (coalesced float4) ----
  const float4* W4 = reinterpret_cast<const float4*>(W);
  const float4* R4 = reinterpret_cast<const float4*>(rel_emb);
  const float4 wst0 = W4[tid];
  const float4 wst1 = W4[512 + tid];
  const float4 rst0 = R4[tid];
  const float4 rst1 = (512 + tid < kRelChunks) ? R4[512 + tid]
                                               : make_float4(0.f, 0.f, 0.f, 0.f);

  // ---- adjacency chain, SCALARIZED (SALU/s_load path) ----
  const int bs    = __builtin_amdgcn_readfirstlane(b);
  const int uid_s = u[bs];
  const int vid_s = v[bs];
  const int e0s   = (vid_s >= kItemInKG) ? kNumEnt : vid_s;  // pad entity

  const float ue  = usr_emb[(size_t)uid_s * kDim + ln];
  const float ev0 = item_emb[(size_t)vid_s * kDim + ln];

  int e1s[kNN];
  {
    const int* __restrict__ a0 = adj_ent + (size_t)e0s * kNN;
    #pragma unroll
    for (int m = 0; m < kNN; ++m) e1s[m] = a0[m];
  }
  int e2s[kDim];
  #pragma unroll
  for (int m = 0; m < kNN; ++m) {
    const int* __restrict__ am = adj_ent + (size_t)e1s[m] * kNN;
    #pragma unroll
    for (int n = 0; n < kNN; ++n) e2s[m * kNN + n] = am[n];
  }
  int r1v = 0;
  if (ln < kNN) r1v = adj_rel[(size_t)e0s * kNN + ln];
  int parent = e1s[0];
  #pragma unroll
  for (int m = 1; m < kNN; ++m)
    parent = ((ln >> 3) == m) ? e1s[m] : parent;
  const int r2v = adj_rel[(size_t)parent * kNN + (ln & 7)];

  // ---- staging writes (fp16 row-major, pad 68) ----
  {
    int id = tid, row = id >> 4, c4 = (id & 15) << 2;
    *reinterpret_cast<f16x4*>(&s_wh[row * kP + c4]) = cvt4(wst0);
    *reinterpret_cast<f16x4*>(&s_relh[row * kP + c4]) = cvt4(rst0);
    id = 512 + tid; row = id >> 4; c4 = (id & 15) << 2;
    *reinterpret_cast<f16x4*>(&s_wh[row * kP + c4]) = cvt4(wst1);
    *reinterpret_cast<f16x4*>(&s_relh[row * kP + c4]) = cvt4(rst1); // 61..63: 0
  }
  s_ueh[wv * kDim + ln] = (_Float16)ue;

  // ---- hop-1 embedding gathers (SGPR ids -> saddr loads) ----
  float ev1r[kNN];
  #pragma unroll
  for (int m = 0; m < kNN; ++m) {
    const size_t row = (size_t)e1s[m] * kDim + ln;
    ev1r[m] = HALF ? __half2float(ent_h[row]) : ent_emb[row];
  }

  // ---- issue ALL 64 hop-2 fp16 gathers now (saddr; pins after softmax) ----
  unsigned short g16[kDim];
  if constexpr (HALF) {
    const unsigned short* eh = reinterpret_cast<const unsigned short*>(ent_h);
    #pragma unroll
    for (int i = 0; i < kDim; ++i)
      g16[i] = eh[(size_t)e2s[i] * kDim + ln];
  }

  __syncthreads();   // staging visible

  // ---- scores via MFMA: t[r] = ue . rel[r] (R12-verified recipe) ----
  f16x8 Au[2];
  #pragma unroll
  for (int s = 0; s < 2; ++s) {
    const _Float16* p = &s_ueh[wv * kDim + s * 32 + lg * 4];
    Au[s] = join8(*reinterpret_cast<const f16x4*>(p),
                  *reinterpret_cast<const f16x4*>(p + 16));
  }
  f32x4 ts[4];
  #pragma unroll
  for (int tt = 0; tt < 4; ++tt) {
    ts[tt] = f32x4{0.f, 0.f, 0.f, 0.f};
    #pragma unroll
    for (int s = 0; s < 2; ++s) {
      const _Float16* p = &s_relh[(tt * 16 + lq) * kP + s * 32 + lg * 4];
      const f16x8 Rf = join8(*reinterpret_cast<const f16x4*>(p),
                             *reinterpret_cast<const f16x4*>(p + 16));
      ts[tt] = __builtin_amdgcn_mfma_f32_16x16x32_f16(Au[s], Rf, ts[tt],
                                                      0, 0, 0);
    }
  }
  auto t_lookup = [&](int r) -> float {
    const int sl = r & 15;
    const float c0 = __shfl(ts[0][0], sl, 64);
    const float c1 = __shfl(ts[1][0], sl, 64);
    const float c2 = __shfl(ts[2][0], sl, 64);
    const float c3 = __shfl(ts[3][0], sl, 64);
    const float ab = (r & 16) ? c1 : c0;
    const float cd = (r & 16) ? c3 : c2;
    return (r & 32) ? cd : ab;
  };

  // ---- softmaxes: 8-lane groups {1,2,4} ----
  {
    const float s2 = t_lookup(r2v);
    float mx = s2;
    #pragma unroll
    for (int m = 1; m <= 4; m <<= 1) mx = fmaxf(mx, __shfl_xor(mx, m, 64));
    const float e = __expf(s2 - mx);
    float sm = e;
    #pragma unroll
    for (int m = 1; m <= 4; m <<= 1) sm += __shfl_xor(sm, m, 64);
    s_w2[wv][ln] = e / sm;
  }
  float w0v;   // lanes 0..7; reused for iter-1
  {
    const float s0 = t_lookup(r1v);
    float mx = s0;
    #pragma unroll
    for (int m = 1; m <= 4; m <<= 1) mx = fmaxf(mx, __shfl_xor(mx, m, 64));
    w0v = __expf(s0 - mx);
    float sm = w0v;
    #pragma unroll
    for (int m = 1; m <= 4; m <<= 1) sm += __shfl_xor(sm, m, 64);
    w0v /= sm;
  }

  if constexpr (HALF) {
    #pragma unroll
    for (int i = 0; i < kDim; ++i) asm volatile("" : "+v"(g16[i]));
  }

  // ---- aggregation (lane = dim) -> fp16 pre-rows in LDS ----
  {
    float agg = 0.f;
    #pragma unroll
    for (int n = 0; n < kNN; ++n)
      agg = fmaf(readlane_f(w0v, n), ev1r[n], agg);
    s_pre[(wv * 9 + 0) * kP + ln] = (_Float16)(ev0 + agg);
  }
  if constexpr (HALF) {
    #pragma unroll
    for (int m = 0; m < kNN; ++m) {
      float acc = 0.f;
      #pragma unroll
      for (int n = 0; n < kNN; ++n) {
        const _Float16 hv = __builtin_bit_cast(_Float16, g16[m * kNN + n]);
        acc = fmaf((float)hv, s_w2[wv][m * kNN + n], acc);
      }
      s_pre[(wv * 9 + 1 + m) * kP + ln] = (_Float16)(ev1r[m] + acc);
    }
  } else {
    #pragma unroll 2
    for (int m = 0; m < kNN; ++m) {
      float acc = 0.f;
      #pragma unroll
      for (int n = 0; n < kNN; ++n) {
        const size_t row = (size_t)e2s[m * kNN + n] * kDim + ln;
        acc = fmaf(s_w2[wv][m * kNN + n], ent_emb[row], acc);
      }
      s_pre[(wv * 9 + 1 + m) * kP + ln] = (_Float16)(ev1r[m] + acc);
    }
  }

  // ---- bias cols ----
  float bcol[4];
  #pragma unroll
  for (int tt = 0; tt < 4; ++tt) bcol[tt] = bias[tt * 16 + lq];

  // ---- B fragments: W^T, cached once ----
  f16x8 Bf[8];
  #pragma unroll
  for (int tt = 0; tt < 4; ++tt) {
    #pragma unroll
    for (int s = 0; s < 2; ++s) {
      const _Float16* p = &s_wh[(tt * 16 + lq) * kP + s * 32 + lg * 4];
      Bf[tt * 2 + s] = join8(*reinterpret_cast<const f16x4*>(p),
                             *reinterpret_cast<const f16x4*>(p + 16));
    }
  }

  // ---- A fragments (own 9 pre-rows; m = lq, clamped) + main GEMM ----
  const int arow = wv * 9 + (lq < 9 ? lq : 8);
  f16x8 Af[2];
  #pragma unroll
  for (int s = 0; s < 2; ++s) {
    const _Float16* p = &s_pre[arow * kP + s * 32 + lg * 4];
    Af[s] = join8(*reinterpret_cast<const f16x4*>(p),
                  *reinterpret_cast<const f16x4*>(p + 16));
  }
  f32x4 acc[4];
  #pragma unroll
  for (int tt = 0; tt < 4; ++tt) acc[tt] = f32x4{0.f, 0.f, 0.f, 0.f};
  #pragma unroll
  for (int tt = 0; tt < 4; ++tt)
    #pragma unroll
    for (int s = 0; s < 2; ++s)
      acc[tt] = __builtin_amdgcn_mfma_f32_16x16x32_f16(Af[s], Bf[tt * 2 + s],
                                                       acc[tt], 0, 0, 0);

  // ---- h = sigmoid(acc + b) written IN PLACE over the pre rows (Af values
  // already bound in registers; in-order DS per wave makes this safe) ----
  #pragma unroll
  for (int tt = 0; tt < 4; ++tt) {
    #pragma unroll
    for (int r = 0; r < 4; ++r) {
      const int vec = lg * 4 + r;
      if (vec < 9)
        s_pre[(wv * 9 + vec) * kP + tt * 16 + lq] =
            (_Float16)fast_sigmoid(acc[tt][r] + bcol[tt]);
    }
  }

  // ---- iter-1 hop-0 (reuse w0), lane = dim; reads h rows then overwrites
  // row 0 (read-before-write in program order per lane; per-lane columns) --
  {
    float pre = (float)s_pre[(wv * 9 + 0) * kP + ln];
    #pragma unroll
    for (int n = 0; n < kNN; ++n)
      pre = fmaf(readlane_f(w0v, n), (float)s_pre[(wv * 9 + 1 + n) * kP + ln],
                 pre);
    s_pre[(wv * 9 + 0) * kP + ln] = (_Float16)pre;
  }

  // ---- final matvec via MFMA: A = pre-row 0 broadcast (uniform read) ----
  f16x8 Ff[2];
  #pragma unroll
  for (int s = 0; s < 2; ++s) {
    const _Float16* p = &s_pre[(wv * 9 + 0) * kP + s * 32 + lg * 4];
    Ff[s] = join8(*reinterpret_cast<const f16x4*>(p),
                  *reinterpret_cast<const f16x4*>(p + 16));
  }
  f32x4 fa[4];
  #pragma unroll
  for (int tt = 0; tt < 4; ++tt) fa[tt] = f32x4{0.f, 0.f, 0.f, 0.f};
  #pragma unroll
  for (int tt = 0; tt < 4; ++tt)
    #pragma unroll
    for (int s = 0; s < 2; ++s)
      fa[tt] = __builtin_amdgcn_mfma_f32_16x16x32_f16(Ff[s], Bf[tt * 2 + s],
                                                      fa[tt], 0, 0, 0);

  // ---- epilogue (R14-verified) ----
  {
    float fown = fa[0][0], bown = bcol[0];
    if (lg == 1) { fown = fa[1][0]; bown = bcol[1]; }
    if (lg == 2) { fown = fa[2][0]; bown = bcol[2]; }
    if (lg == 3) { fown = fa[3][0]; bown = bcol[3]; }
    float part = fast_tanh(fown + bown) * ue;
    #pragma unroll
    for (int off = 32; off > 0; off >>= 1)
      part += __shfl_xor(part, off, 64);
    if (ln == 0) out[b] = fast_sigmoid(part);
  }
}

}  // namespace

extern "C" void kernel_launch(void* const* d_in, const int* in_sizes, int n_in,
                              void* d_out, int out_size, void* d_ws, size_t ws_size,
                              hipStream_t stream) {
  const int*   u        = (const int*)d_in[0];
  const int*   v        = (const int*)d_in[1];
  const float* usr_emb  = (const float*)d_in[2];
  const float* item_emb = (const float*)d_in[3];
  const float* ent_emb  = (const float*)d_in[4];
  const float* rel_emb  = (const float*)d_in[5];
  const float* W        = (const float*)d_in[6];
  const float* bias     = (const float*)d_in[7];
  const int*   adj_ent  = (const int*)d_in[8];
  const int*   adj_rel  = (const int*)d_in[9];
  float*       out      = (float*)d_out;

  const int B = in_sizes[0];   // 16384, divisible by kElems=8
  dim3 grid(B / kElems), block(kElems * 64);

  const bool use_half = (ws_size >= kEntHalfBytes);
  if (use_half) {
    __half* ent_h = (__half*)d_ws;
    const int n4 = (kNumEnt + 1) * kDim / 4;
    hipLaunchKernelGGL(conv_kernel, dim3((n4 + 255) / 256), dim3(256), 0,
                       stream, ent_emb, (__half2*)ent_h, n4);
    hipLaunchKernelGGL((kgcn_kernel<true>), grid, block, 0, stream,
                       u, v, usr_emb, item_emb, ent_emb, ent_h, rel_emb, W,
                       bias, adj_ent, adj_rel, out);
  } else {
    hipLaunchKernelGGL((kgcn_kernel<false>), grid, block, 0, stream,
                       u, v, usr_emb, item_emb, ent_emb, (const __half*)d_ws,
                       rel_emb, W, bias, adj_ent, adj_rel, out);
  }
}

// Round 19
// 52.142 us; speedup vs baseline: 1.5204x; 1.5204x over previous
//
#include <hip/hip_runtime.h>
#include <hip/hip_fp16.h>

// KGCN forward, MI355X. R19 = exact revert to R17/R15 (verified best:
// 44.2us kernel, 4.3x over baseline). R18's s_h->s_pre aliasing serialized
// the GEMM tail (compiler lgkmcnt(0) ordering around the in-place buffer;
// VALUBusy 43->22%, dur 2x) AND proved occupancy was never LDS-capped
// (4-block config ran at the same ~32%). Combined with R5/R16 (register
// ceilings block deeper per-wave MLP) and R10/R11 (allocator pins the
// 64-VGPR tier), the kernel sits at the structural latency floor: per
// element, the dependency chain u/v -> e1 s_loads -> e2 s_loads -> 72
// random row-gathers -> agg -> GEMM is ~4.5-5k cycles; at ~11 resident
// waves/CU this yields exactly the measured ~44us. No pipe is saturated
// (VALU 43%, LDS ~25%, MFMA 5%, HBM 27%) -- the time is latency, and all
// concurrency levers (occupancy, per-wave MLP, 2-elem pipelining) are
// blocked by measured hardware limits.

namespace {

constexpr int kDim      = 64;
constexpr int kNN       = 8;
constexpr int kNumEnt   = 100000;
constexpr int kItemInKG = 20000;
constexpr int kElems    = 8;     // batch elements (waves) per block
constexpr int kRelChunks = 976;  // 61 rel rows * 16 float4 chunks
constexpr int kP        = 68;    // fp16 row stride (136B)
constexpr size_t kEntHalfBytes = (size_t)(kNumEnt + 1) * kDim * sizeof(__half);

typedef _Float16 f16x4 __attribute__((ext_vector_type(4)));
typedef _Float16 f16x8 __attribute__((ext_vector_type(8)));
typedef float    f32x4 __attribute__((ext_vector_type(4)));

__device__ __forceinline__ float fast_sigmoid(float x) {
  return 1.0f / (1.0f + __expf(-x));
}
__device__ __forceinline__ float fast_tanh(float x) {
  return 2.0f / (1.0f + __expf(-2.0f * x)) - 1.0f;
}
__device__ __forceinline__ float readlane_f(float v, int lane) {
  return __int_as_float(__builtin_amdgcn_readlane(__float_as_int(v), lane));
}
__device__ __forceinline__ f16x8 join8(f16x4 lo, f16x4 hi) {
  return __builtin_shufflevector(lo, hi, 0, 1, 2, 3, 4, 5, 6, 7);
}
__device__ __forceinline__ f16x4 cvt4(float4 f) {
  f16x4 h;
  h[0] = (_Float16)f.x; h[1] = (_Float16)f.y;
  h[2] = (_Float16)f.z; h[3] = (_Float16)f.w;
  return h;
}

// ---- pre-pass: ent_emb fp32 -> fp16 into workspace ----
__global__ void __launch_bounds__(256)
conv_kernel(const float* __restrict__ src, __half2* __restrict__ dst, int n4) {
  const int i = blockIdx.x * 256 + threadIdx.x;
  if (i < n4) {
    const float4 f = reinterpret_cast<const float4*>(src)[i];
    dst[2 * i + 0] = __floats2half2_rn(f.x, f.y);
    dst[2 * i + 1] = __floats2half2_rn(f.z, f.w);
  }
}

template <bool HALF>
__global__ void __launch_bounds__(kElems * 64)
__attribute__((amdgpu_waves_per_eu(4)))
kgcn_kernel(const int* __restrict__ u, const int* __restrict__ v,
            const float* __restrict__ usr_emb, const float* __restrict__ item_emb,
            const float* __restrict__ ent_emb, const __half* __restrict__ ent_h,
            const float* __restrict__ rel_emb,
            const float* __restrict__ W, const float* __restrict__ bias,
            const int* __restrict__ adj_ent, const int* __restrict__ adj_rel,
            float* __restrict__ out)
{
  const int tid = threadIdx.x;
  const int wv  = tid >> 6;
  const int ln  = tid & 63;
  const int lq  = ln & 15;    // MFMA m/n index
  const int lg  = ln >> 4;    // MFMA k-slot group
  const int b   = blockIdx.x * kElems + wv;

  __shared__ __align__(16) _Float16 s_wh[kDim * kP];      // 8,704 B
  __shared__ __align__(16) _Float16 s_relh[kDim * kP];    // 8,704 B
  __shared__ __align__(16) _Float16 s_ueh[kElems * kDim]; // 1,024 B
  __shared__ __align__(16) _Float16 s_pre[72 * kP];       // 9,792 B
  __shared__ __align__(16) _Float16 s_h[72 * kP];         // 9,792 B
  __shared__ float s_w2[kElems][kDim];                    // 2,048 B

  // ---- staging loads (coalesced float4) ----
  const float4* W4 = reinterpret_cast<const float4*>(W);
  const float4* R4 = reinterpret_cast<const float4*>(rel_emb);
  const float4 wst0 = W4[tid];
  const float4 wst1 = W4[512 + tid];
  const float4 rst0 = R4[tid];
  const float4 rst1 = (512 + tid < kRelChunks) ? R4[512 + tid]
                                               : make_float4(0.f, 0.f, 0.f, 0.f);

  // ---- adjacency chain, SCALARIZED: b is wave-uniform -> force SGPR and
  // let the whole id tree ride the SALU/s_load path.
  const int bs    = __builtin_amdgcn_readfirstlane(b);
  const int uid_s = u[bs];                                   // s_load
  const int vid_s = v[bs];                                   // s_load
  const int e0s   = (vid_s >= kItemInKG) ? kNumEnt : vid_s;  // pad entity

  const float ue  = usr_emb[(size_t)uid_s * kDim + ln];      // saddr vec load
  const float ev0 = item_emb[(size_t)vid_s * kDim + ln];

  int e1s[kNN];
  {
    const int* __restrict__ a0 = adj_ent + (size_t)e0s * kNN;
    #pragma unroll
    for (int m = 0; m < kNN; ++m) e1s[m] = a0[m];            // s_load x8
  }
  int e2s[kDim];
  #pragma unroll
  for (int m = 0; m < kNN; ++m) {
    const int* __restrict__ am = adj_ent + (size_t)e1s[m] * kNN;
    #pragma unroll
    for (int n = 0; n < kNN; ++n) e2s[m * kNN + n] = am[n];  // s_load x8 each
  }
  // per-lane relation ids (vector; feed the per-lane softmax)
  int r1v = 0;
  if (ln < kNN) r1v = adj_rel[(size_t)e0s * kNN + ln];
  int parent = e1s[0];
  #pragma unroll
  for (int m = 1; m < kNN; ++m)
    parent = ((ln >> 3) == m) ? e1s[m] : parent;   // SGPR select by lane group
  const int r2v = adj_rel[(size_t)parent * kNN + (ln & 7)];

  // ---- staging writes (fp16 row-major, pad 68) ----
  {
    int id = tid, row = id >> 4, c4 = (id & 15) << 2;
    *reinterpret_cast<f16x4*>(&s_wh[row * kP + c4]) = cvt4(wst0);
    *reinterpret_cast<f16x4*>(&s_relh[row * kP + c4]) = cvt4(rst0);
    id = 512 + tid; row = id >> 4; c4 = (id & 15) << 2;
    *reinterpret_cast<f16x4*>(&s_wh[row * kP + c4]) = cvt4(wst1);
    *reinterpret_cast<f16x4*>(&s_relh[row * kP + c4]) = cvt4(rst1); // 61..63: 0
  }
  s_ueh[wv * kDim + ln] = (_Float16)ue;

  // ---- hop-1 embedding gathers (SGPR ids -> saddr loads) ----
  float ev1r[kNN];
  #pragma unroll
  for (int m = 0; m < kNN; ++m) {
    const size_t row = (size_t)e1s[m] * kDim + ln;
    ev1r[m] = HALF ? __half2float(ent_h[row]) : ent_emb[row];
  }

  // ---- issue ALL 64 hop-2 fp16 gathers now (SGPR ids -> saddr, zero VALU
  // address math; pins after softmax keep them un-sinkable).
  unsigned short g16[kDim];
  if constexpr (HALF) {
    const unsigned short* eh = reinterpret_cast<const unsigned short*>(ent_h);
    #pragma unroll
    for (int i = 0; i < kDim; ++i)
      g16[i] = eh[(size_t)e2s[i] * kDim + ln];
  }

  __syncthreads();   // staging visible

  // ---- scores via MFMA: t[r] = ue . rel[r] (R12-verified recipe) ----
  f16x8 Au[2];
  #pragma unroll
  for (int s = 0; s < 2; ++s) {
    const _Float16* p = &s_ueh[wv * kDim + s * 32 + lg * 4];
    Au[s] = join8(*reinterpret_cast<const f16x4*>(p),
                  *reinterpret_cast<const f16x4*>(p + 16));
  }
  f32x4 ts[4];
  #pragma unroll
  for (int tt = 0; tt < 4; ++tt) {
    ts[tt] = f32x4{0.f, 0.f, 0.f, 0.f};
    #pragma unroll
    for (int s = 0; s < 2; ++s) {
      const _Float16* p = &s_relh[(tt * 16 + lq) * kP + s * 32 + lg * 4];
      const f16x8 Rf = join8(*reinterpret_cast<const f16x4*>(p),
                             *reinterpret_cast<const f16x4*>(p + 16));
      ts[tt] = __builtin_amdgcn_mfma_f32_16x16x32_f16(Au[s], Rf, ts[tt],
                                                      0, 0, 0);
    }
  }
  // t[r] lives on lane (r&15) in ts[r>>4][0] (all D rows identical).
  auto t_lookup = [&](int r) -> float {
    const int sl = r & 15;
    const float c0 = __shfl(ts[0][0], sl, 64);
    const float c1 = __shfl(ts[1][0], sl, 64);
    const float c2 = __shfl(ts[2][0], sl, 64);
    const float c3 = __shfl(ts[3][0], sl, 64);
    const float ab = (r & 16) ? c1 : c0;
    const float cd = (r & 16) ? c3 : c2;
    return (r & 32) ? cd : ab;
  };

  // ---- softmaxes: 8-lane groups {1,2,4} ----
  {
    const float s2 = t_lookup(r2v);
    float mx = s2;
    #pragma unroll
    for (int m = 1; m <= 4; m <<= 1) mx = fmaxf(mx, __shfl_xor(mx, m, 64));
    const float e = __expf(s2 - mx);
    float sm = e;
    #pragma unroll
    for (int m = 1; m <= 4; m <<= 1) sm += __shfl_xor(sm, m, 64);
    s_w2[wv][ln] = e / sm;   // broadcast via LDS (same-addr reads are free)
  }
  float w0v;   // lanes 0..7; reused for iter-1
  {
    const float s0 = t_lookup(r1v);
    float mx = s0;
    #pragma unroll
    for (int m = 1; m <= 4; m <<= 1) mx = fmaxf(mx, __shfl_xor(mx, m, 64));
    w0v = __expf(s0 - mx);
    float sm = w0v;
    #pragma unroll
    for (int m = 1; m <= 4; m <<= 1) sm += __shfl_xor(sm, m, 64);
    w0v /= sm;
  }

  if constexpr (HALF) {
    #pragma unroll
    for (int i = 0; i < kDim; ++i) asm volatile("" : "+v"(g16[i]));
  }

  // ---- aggregation (lane = dim) -> fp16 pre-rows in LDS ----
  {
    float agg = 0.f;
    #pragma unroll
    for (int n = 0; n < kNN; ++n)
      agg = fmaf(readlane_f(w0v, n), ev1r[n], agg);
    s_pre[(wv * 9 + 0) * kP + ln] = (_Float16)(ev0 + agg);
  }
  if constexpr (HALF) {
    #pragma unroll
    for (int m = 0; m < kNN; ++m) {
      float acc = 0.f;
      #pragma unroll
      for (int n = 0; n < kNN; ++n) {
        // (float)f16 * f32 + f32 -> v_fma_mix candidate; w2 from LDS
        const _Float16 hv =
            __builtin_bit_cast(_Float16, g16[m * kNN + n]);
        acc = fmaf((float)hv, s_w2[wv][m * kNN + n], acc);
      }
      s_pre[(wv * 9 + 1 + m) * kP + ln] = (_Float16)(ev1r[m] + acc);
    }
  } else {
    #pragma unroll 2
    for (int m = 0; m < kNN; ++m) {
      float acc = 0.f;
      #pragma unroll
      for (int n = 0; n < kNN; ++n) {
        const size_t row = (size_t)e2s[m * kNN + n] * kDim + ln;
        acc = fmaf(s_w2[wv][m * kNN + n], ent_emb[row], acc);
      }
      s_pre[(wv * 9 + 1 + m) * kP + ln] = (_Float16)(ev1r[m] + acc);
    }
  }

  // ---- bias cols for this lane's D columns ----
  float bcol[4];
  #pragma unroll
  for (int tt = 0; tt < 4; ++tt) bcol[tt] = bias[tt * 16 + lq];

  // ---- B fragments: W^T, cached once ----
  f16x8 Bf[8];
  #pragma unroll
  for (int tt = 0; tt < 4; ++tt) {
    #pragma unroll
    for (int s = 0; s < 2; ++s) {
      const _Float16* p = &s_wh[(tt * 16 + lq) * kP + s * 32 + lg * 4];
      Bf[tt * 2 + s] = join8(*reinterpret_cast<const f16x4*>(p),
                             *reinterpret_cast<const f16x4*>(p + 16));
    }
  }

  // ---- A fragments (own 9 pre-rows; m = lq, clamped) + main GEMM ----
  const int arow = wv * 9 + (lq < 9 ? lq : 8);
  f16x8 Af[2];
  #pragma unroll
  for (int s = 0; s < 2; ++s) {
    const _Float16* p = &s_pre[arow * kP + s * 32 + lg * 4];
    Af[s] = join8(*reinterpret_cast<const f16x4*>(p),
                  *reinterpret_cast<const f16x4*>(p + 16));
  }
  f32x4 acc[4];
  #pragma unroll
  for (int tt = 0; tt < 4; ++tt) acc[tt] = f32x4{0.f, 0.f, 0.f, 0.f};
  #pragma unroll
  for (int tt = 0; tt < 4; ++tt)
    #pragma unroll
    for (int s = 0; s < 2; ++s)
      acc[tt] = __builtin_amdgcn_mfma_f32_16x16x32_f16(Af[s], Bf[tt * 2 + s],
                                                       acc[tt], 0, 0, 0);

  // ---- h = sigmoid(acc + b): D row=(lg*4+r)=vec, col=tt*16+lq ----
  #pragma unroll
  for (int tt = 0; tt < 4; ++tt) {
    #pragma unroll
    for (int r = 0; r < 4; ++r) {
      const int vec = lg * 4 + r;
      if (vec < 9)
        s_h[(wv * 9 + vec) * kP + tt * 16 + lq] =
            (_Float16)fast_sigmoid(acc[tt][r] + bcol[tt]);
    }
  }

  // ---- iter-1 hop-0 (reuse w0), lane = dim; overwrite pre-row 0 ----
  {
    float pre = (float)s_h[(wv * 9 + 0) * kP + ln];
    #pragma unroll
    for (int n = 0; n < kNN; ++n)
      pre = fmaf(readlane_f(w0v, n), (float)s_h[(wv * 9 + 1 + n) * kP + ln],
                 pre);
    s_pre[(wv * 9 + 0) * kP + ln] = (_Float16)pre;
  }

  // ---- final matvec via MFMA: A = pre-row 0 broadcast (uniform read) ----
  f16x8 Ff[2];
  #pragma unroll
  for (int s = 0; s < 2; ++s) {
    const _Float16* p = &s_pre[(wv * 9 + 0) * kP + s * 32 + lg * 4];
    Ff[s] = join8(*reinterpret_cast<const f16x4*>(p),
                  *reinterpret_cast<const f16x4*>(p + 16));
  }
  f32x4 fa[4];
  #pragma unroll
  for (int tt = 0; tt < 4; ++tt) fa[tt] = f32x4{0.f, 0.f, 0.f, 0.f};
  #pragma unroll
  for (int tt = 0; tt < 4; ++tt)
    #pragma unroll
    for (int s = 0; s < 2; ++s)
      fa[tt] = __builtin_amdgcn_mfma_f32_16x16x32_f16(Ff[s], Bf[tt * 2 + s],
                                                      fa[tt], 0, 0, 0);

  // ---- epilogue (R14-verified): lane ln = lg*16+lq holds item[ln] in
  // fa[lg][0]; static-index select, multiply by own ue, butterfly reduce.
  {
    float fown = fa[0][0], bown = bcol[0];
    if (lg == 1) { fown = fa[1][0]; bown = bcol[1]; }
    if (lg == 2) { fown = fa[2][0]; bown = bcol[2]; }
    if (lg == 3) { fown = fa[3][0]; bown = bcol[3]; }
    float part = fast_tanh(fown + bown) * ue;
    #pragma unroll
    for (int off = 32; off > 0; off >>= 1)
      part += __shfl_xor(part, off, 64);
    if (ln == 0) out[b] = fast_sigmoid(part);
  }
}

}  // namespace

extern "C" void kernel_launch(void* const* d_in, const int* in_sizes, int n_in,
                              void* d_out, int out_size, void* d_ws, size_t ws_size,
                              hipStream_t stream) {
  const int*   u        = (const int*)d_in[0];
  const int*   v        = (const int*)d_in[1];
  const float* usr_emb  = (const float*)d_in[2];
  const float* item_emb = (const float*)d_in[3];
  const float* ent_emb  = (const float*)d_in[4];
  const float* rel_emb  = (const float*)d_in[5];
  const float* W        = (const float*)d_in[6];
  const float* bias     = (const float*)d_in[7];
  const int*   adj_ent  = (const int*)d_in[8];
  const int*   adj_rel  = (const int*)d_in[9];
  float*       out      = (float*)d_out;

  const int B = in_sizes[0];   // 16384, divisible by kElems=8
  dim3 grid(B / kElems), block(kElems * 64);

  const bool use_half = (ws_size >= kEntHalfBytes);
  if (use_half) {
    __half* ent_h = (__half*)d_ws;
    const int n4 = (kNumEnt + 1) * kDim / 4;
    hipLaunchKernelGGL(conv_kernel, dim3((n4 + 255) / 256), dim3(256), 0,
                       stream, ent_emb, (__half2*)ent_h, n4);
    hipLaunchKernelGGL((kgcn_kernel<true>), grid, block, 0, stream,
                       u, v, usr_emb, item_emb, ent_emb, ent_h, rel_emb, W,
                       bias, adj_ent, adj_rel, out);
  } else {
    hipLaunchKernelGGL((kgcn_kernel<false>), grid, block, 0, stream,
                       u, v, usr_emb, item_emb, ent_emb, (const __half*)d_ws,
                       rel_emb, W, bias, adj_ent, adj_rel, out);
  }
}